// Round 1
// baseline (172.906 us; speedup 1.0000x reference)
//
#include <hip/hip_runtime.h>
#include <hip/hip_bf16.h>

// Problem constants
#define NB    4096          // batch
#define ND    256           // dim
#define NP    2             // positives per anchor
#define TOT   (NB * 3)      // 12288 rows: [a | p0 | p1]
#define NCHUNK 16
#define COLS_PER_CHUNK (TOT / NCHUNK)     // 768
#define TILES_PER_CHUNK (COLS_PER_CHUNK / 16)  // 48
#define NEG_INIT (-4.0f)

typedef __bf16 bf16x8 __attribute__((ext_vector_type(8)));
typedef float  f32x4  __attribute__((ext_vector_type(4)));

// ws layout (bytes)
#define WS_F_OFF    0                            // ushort[12288*256] bf16 normalized
#define WS_POS_OFF  (TOT * ND * 2)               // float[4096*2] pos distances
#define WS_PART_OFF (WS_POS_OFF + NB * NP * 4)   // float[NCHUNK*4096*3] partial maxima

__device__ __forceinline__ unsigned short f2bf(float f) {
    unsigned u = __float_as_uint(f);
    u += 0x7fffu + ((u >> 16) & 1u);   // round-to-nearest-even
    return (unsigned short)(u >> 16);
}

// Kernel 1: normalize rows of [a | p0 | p1] -> bf16 matrix F.
// One wave per row; lane handles 4 consecutive floats.
__global__ void norm_kernel(const float* __restrict__ anchor,
                            const float* __restrict__ positive,
                            unsigned short* __restrict__ F) {
    int wid = threadIdx.x >> 6, lane = threadIdx.x & 63;
    int row = blockIdx.x * 4 + wid;              // grid = 3072
    const float* src;
    if (row < NB) {
        src = anchor + (size_t)row * ND;
    } else {
        int q = row - NB;
        int v = q >> 12;                         // 0 or 1
        int j = q & (NB - 1);
        src = positive + (size_t)(j * NP + v) * ND;
    }
    float4 x = *(const float4*)(src + lane * 4);
    float ss = x.x * x.x + x.y * x.y + x.z * x.z + x.w * x.w;
    #pragma unroll
    for (int m = 1; m < 64; m <<= 1) ss += __shfl_xor(ss, m, 64);
    float inv = 1.0f / fmaxf(sqrtf(ss), 1e-12f);
    ushort4 o;
    o.x = f2bf(x.x * inv);
    o.y = f2bf(x.y * inv);
    o.z = f2bf(x.z * inv);
    o.w = f2bf(x.w * inv);
    *(ushort4*)(F + (size_t)row * ND + lane * 4) = o;
}

// Kernel 2: exact fp32 positive distances. One wave per (i, v) pair.
__global__ void pos_kernel(const float* __restrict__ anchor,
                           const float* __restrict__ positive,
                           float* __restrict__ posArr) {
    int wid = threadIdx.x >> 6, lane = threadIdx.x & 63;
    int pair = blockIdx.x * 4 + wid;             // grid = 2048, pairs 0..8191
    int i = pair >> 1, v = pair & 1;
    const float* pa = anchor + (size_t)i * ND;
    const float* pp = positive + (size_t)(i * NP + v) * ND;
    float4 xa = *(const float4*)(pa + lane * 4);
    float4 xp = *(const float4*)(pp + lane * 4);
    float dot = xa.x * xp.x + xa.y * xp.y + xa.z * xp.z + xa.w * xp.w;
    float sa  = xa.x * xa.x + xa.y * xa.y + xa.z * xa.z + xa.w * xa.w;
    float sp  = xp.x * xp.x + xp.y * xp.y + xp.z * xp.z + xp.w * xp.w;
    #pragma unroll
    for (int m = 1; m < 64; m <<= 1) {
        dot += __shfl_xor(dot, m, 64);
        sa  += __shfl_xor(sa, m, 64);
        sp  += __shfl_xor(sp, m, 64);
    }
    if (lane == 0) {
        float inva = 1.0f / fmaxf(sqrtf(sa), 1e-12f);
        float invp = 1.0f / fmaxf(sqrtf(sp), 1e-12f);
        float dn = dot * inva * invp;
        float sq = 2.0f - 2.0f * dn;
        posArr[pair] = sqrtf(fmaxf(sq, 1e-12f));
    }
}

// Kernel 3: fused masked-max Gram. Each wave: 32 anchor rows (2 x 16-row MFMA
// sets, A frags register-resident) x 768-column chunk. Running per-part max.
__global__ __launch_bounds__(256) void gram_max_kernel(
        const unsigned short* __restrict__ F,
        const int* __restrict__ labels,
        float* __restrict__ partials) {
    int wid = threadIdx.x >> 6, lane = threadIdx.x & 63;
    int l15 = lane & 15, quad = lane >> 4;
    int rowBase = blockIdx.x * 128 + wid * 32;   // gridDim.x = 32
    int chunk = blockIdx.y;                      // gridDim.y = NCHUNK

    // Preload A fragments: af[s][kk] covers rows rowBase+s*16.. , K = kk*32
    bf16x8 af[2][8];
    #pragma unroll
    for (int s = 0; s < 2; ++s) {
        const unsigned short* ar = F + (size_t)(rowBase + s * 16 + l15) * ND + quad * 8;
        #pragma unroll
        for (int kk = 0; kk < 8; ++kk)
            af[s][kk] = *(const bf16x8*)(ar + kk * 32);
    }
    // Row labels for this lane's 8 C rows (C layout: row = quad*4 + reg)
    int rl[2][4];
    #pragma unroll
    for (int s = 0; s < 2; ++s)
        #pragma unroll
        for (int r = 0; r < 4; ++r)
            rl[s][r] = labels[rowBase + s * 16 + quad * 4 + r];

    float vmax0[2][4], vmax1[2][4], vmax2[2][4];
    #pragma unroll
    for (int s = 0; s < 2; ++s)
        #pragma unroll
        for (int r = 0; r < 4; ++r) {
            vmax0[s][r] = NEG_INIT; vmax1[s][r] = NEG_INIT; vmax2[s][r] = NEG_INIT;
        }

    for (int ct = 0; ct < TILES_PER_CHUNK; ++ct) {
        int colBase = chunk * COLS_PER_CHUNK + ct * 16;
        int part = colBase >> 12;                // wave-uniform: 0=aa, 1=p0, 2=p1
        int c = colBase + l15;
        const unsigned short* br = F + (size_t)c * ND + quad * 8;
        bf16x8 bf[8];
        #pragma unroll
        for (int kk = 0; kk < 8; ++kk)
            bf[kk] = *(const bf16x8*)(br + kk * 32);

        f32x4 acc0 = {0.f, 0.f, 0.f, 0.f};
        f32x4 acc1 = {0.f, 0.f, 0.f, 0.f};
        #pragma unroll
        for (int kk = 0; kk < 8; ++kk) {
            acc0 = __builtin_amdgcn_mfma_f32_16x16x32_bf16(af[0][kk], bf[kk], acc0, 0, 0, 0);
            acc1 = __builtin_amdgcn_mfma_f32_16x16x32_bf16(af[1][kk], bf[kk], acc1, 0, 0, 0);
        }
        int lc = labels[c & (NB - 1)];           // column label (shared mod NB)

        if (part == 0) {
            #pragma unroll
            for (int r = 0; r < 4; ++r) {
                float c0 = (lc != rl[0][r]) ? acc0[r] : NEG_INIT;
                float c1 = (lc != rl[1][r]) ? acc1[r] : NEG_INIT;
                vmax0[0][r] = fmaxf(vmax0[0][r], c0);
                vmax0[1][r] = fmaxf(vmax0[1][r], c1);
            }
        } else if (part == 1) {
            #pragma unroll
            for (int r = 0; r < 4; ++r) {
                float c0 = (lc != rl[0][r]) ? acc0[r] : NEG_INIT;
                float c1 = (lc != rl[1][r]) ? acc1[r] : NEG_INIT;
                vmax1[0][r] = fmaxf(vmax1[0][r], c0);
                vmax1[1][r] = fmaxf(vmax1[1][r], c1);
            }
        } else {
            #pragma unroll
            for (int r = 0; r < 4; ++r) {
                float c0 = (lc != rl[0][r]) ? acc0[r] : NEG_INIT;
                float c1 = (lc != rl[1][r]) ? acc1[r] : NEG_INIT;
                vmax2[0][r] = fmaxf(vmax2[0][r], c0);
                vmax2[1][r] = fmaxf(vmax2[1][r], c1);
            }
        }
    }

    // Reduce max across the 16 column-lanes (same quad = same rows)
    #pragma unroll
    for (int m = 1; m < 16; m <<= 1) {
        #pragma unroll
        for (int s = 0; s < 2; ++s)
            #pragma unroll
            for (int r = 0; r < 4; ++r) {
                vmax0[s][r] = fmaxf(vmax0[s][r], __shfl_xor(vmax0[s][r], m, 64));
                vmax1[s][r] = fmaxf(vmax1[s][r], __shfl_xor(vmax1[s][r], m, 64));
                vmax2[s][r] = fmaxf(vmax2[s][r], __shfl_xor(vmax2[s][r], m, 64));
            }
    }
    if (l15 == 0) {
        #pragma unroll
        for (int s = 0; s < 2; ++s)
            #pragma unroll
            for (int r = 0; r < 4; ++r) {
                int row = rowBase + s * 16 + quad * 4 + r;
                float* o = partials + (size_t)(chunk * NB + row) * 3;
                o[0] = vmax0[s][r];
                o[1] = vmax1[s][r];
                o[2] = vmax2[s][r];
            }
    }
}

// Kernel 4: combine chunk partials -> neg distances -> hinge loss -> mean.
__global__ void finalize_kernel(const float* __restrict__ partials,
                                const float* __restrict__ posArr,
                                float* __restrict__ out) {
    int row = blockIdx.x * 256 + threadIdx.x;    // grid = 16 -> 4096 rows
    float ma = NEG_INIT, m0 = NEG_INIT, m1 = NEG_INIT;
    for (int c = 0; c < NCHUNK; ++c) {
        const float* pp = partials + (size_t)(c * NB + row) * 3;
        ma = fmaxf(ma, pp[0]);
        m0 = fmaxf(m0, pp[1]);
        m1 = fmaxf(m1, pp[2]);
    }
    float n0 = sqrtf(fmaxf(2.0f - 2.0f * fmaxf(ma, m0), 1e-12f));
    float n1 = sqrtf(fmaxf(2.0f - 2.0f * fmaxf(ma, m1), 1e-12f));
    float l = fmaxf(posArr[row * 2 + 0] - n0 + 1.0f, 0.0f)
            + fmaxf(posArr[row * 2 + 1] - n1 + 1.0f, 0.0f);
    // block sum
    int lane = threadIdx.x & 63, wid = threadIdx.x >> 6;
    #pragma unroll
    for (int m = 1; m < 64; m <<= 1) l += __shfl_xor(l, m, 64);
    __shared__ float wsum[4];
    if (lane == 0) wsum[wid] = l;
    __syncthreads();
    if (threadIdx.x == 0) {
        float s = wsum[0] + wsum[1] + wsum[2] + wsum[3];
        atomicAdd(out, s * (1.0f / (NB * NP)));
    }
}

extern "C" void kernel_launch(void* const* d_in, const int* in_sizes, int n_in,
                              void* d_out, int out_size, void* d_ws, size_t ws_size,
                              hipStream_t stream) {
    const float* anchor   = (const float*)d_in[0];
    const float* positive = (const float*)d_in[1];
    const int*   labels   = (const int*)d_in[2];
    float* out = (float*)d_out;

    unsigned short* F = (unsigned short*)((char*)d_ws + WS_F_OFF);
    float* posArr     = (float*)((char*)d_ws + WS_POS_OFF);
    float* partials   = (float*)((char*)d_ws + WS_PART_OFF);

    norm_kernel<<<TOT / 4, 256, 0, stream>>>(anchor, positive, F);
    pos_kernel<<<(NB * NP) / 4, 256, 0, stream>>>(anchor, positive, posArr);
    gram_max_kernel<<<dim3(NB / 128, NCHUNK), 256, 0, stream>>>(F, labels, partials);
    hipMemsetAsync(d_out, 0, sizeof(float), stream);
    finalize_kernel<<<NB / 256, 256, 0, stream>>>(partials, posArr, out);
}